// Round 1
// baseline (235.715 us; speedup 1.0000x reference)
//
#include <hip/hip_runtime.h>

#define NB 64        // bins
#define HW 65536     // pixels per channel (256*256)
#define NCH 24       // B*C = 8*3
#define SPLIT 32     // segments per channel-image
#define RAD 5        // truncation radius: dropped mass < 1.5e-7 relative
#define NSLOT 74     // padded bins: slot = bin + RAD, bin in [-5, 68]

// w_j(x) = exp(-2048*(x - j/63)^2) = exp(-K*(f-j)^2), f = 63x, K = 2048/3969.
// For j = ni + r (ni = round(f), d = f - ni):
//   w = exp(-K*(d-r)^2) = w0 * (e^{2Kd})^r * C_r,  w0 = e^{-K d^2}, C_r = e^{-K r^2}
// -> 3 transcendentals per pixel, 11 taps (|r| <= 5).
//
// Accumulation: per-LANE LDS columns h[slot][lane] (64 cols) via hardware
// ds_add_f32 atomics (native fp32 LDS atomic on gfx950, no return, no CAS).
//   - 11 DS ops/pixel instead of 22 (read+write RMW), and no read->add->write
//     dependency chain: atomics are fire-and-forget.
//   - LDS = 74*64*4 = 18.9 KB/block -> 8 blocks/CU (vs 75.8 KB -> 2 blocks/CU):
//     32 waves/CU hides DS/trans latency that previously stalled 2 waves/SIMD.
//   - bank = lane%32 uniform 2-way (free); cross-wave same-address collisions
//     serialize in the LDS atomic unit within the same 2-lane/bank budget.
__global__ __launch_bounds__(256) void chml_hist(const float* __restrict__ pred,
                                                 const float* __restrict__ targ,
                                                 float* __restrict__ part) {
  const int seg = blockIdx.x;   // 0..SPLIT-1
  const int ct  = blockIdx.y;   // 0..2*NCH-1
  const float* src = (ct < NCH) ? (pred + (size_t)ct * HW)
                                : (targ + (size_t)(ct - NCH) * HW);
  const int tid  = threadIdx.x;
  const int lane = tid & 63;

  __shared__ float h[NSLOT][NB];   // [slot][lane-column]
  {
    float4* hz = (float4*)&h[0][0];
#pragma unroll 2
    for (int i = tid; i < NSLOT * NB / 4; i += 256)
      hz[i] = make_float4(0.f, 0.f, 0.f, 0.f);
  }
  __syncthreads();

  const float K  = 0.51599899f;      // 2048/3969
  const float C1 = 5.96905619e-01f;  // exp(-K*1)
  const float C2 = 1.26927917e-01f;  // exp(-K*4)
  const float C3 = 9.61165782e-03f;  // exp(-K*9)
  const float C4 = 2.59240329e-04f;  // exp(-K*16)
  const float C5 = 2.49029640e-06f;  // exp(-K*25)

  // segment = 2048 elems = 512 float4; 256 threads x 2 iterations, coalesced
  const float4* s4 = (const float4*)(src + (size_t)seg * (HW / SPLIT));
  float* const colbase = &h[0][lane];
#pragma unroll
  for (int k = 0; k < (HW / SPLIT) / (4 * 256); ++k) {
    float4 p = s4[k * 256 + tid];
    float pe[4] = {p.x, p.y, p.z, p.w};
#pragma unroll
    for (int e = 0; e < 4; ++e) {
      float f = pe[e] * 63.0f;
      float n = rintf(f);
      float d = f - n;            // [-0.5, 0.5]
      int  ni = (int)n;           // 0..63
      float w0 = __expf(d * d * -K);
      float mp = __expf(d * (2.0f * K));   // e^{+2Kd}
      float mn = __expf(d * (-2.0f * K));  // e^{-2Kd}
      float mp2 = mp * mp, mp3 = mp2 * mp, mp4 = mp2 * mp2, mp5 = mp4 * mp;
      float mn2 = mn * mn, mn3 = mn2 * mn, mn4 = mn2 * mn2, mn5 = mn4 * mn;
      float A1 = w0 * C1, A2 = w0 * C2, A3 = w0 * C3, A4 = w0 * C4, A5 = w0 * C5;
      float w[11];
      w[0]  = A5 * mn5;  // r = -5  -> slot ni+0
      w[1]  = A4 * mn4;
      w[2]  = A3 * mn3;
      w[3]  = A2 * mn2;
      w[4]  = A1 * mn;
      w[5]  = w0;        // r = 0   -> slot ni+5
      w[6]  = A1 * mp;
      w[7]  = A2 * mp2;
      w[8]  = A3 * mp3;
      w[9]  = A4 * mp4;
      w[10] = A5 * mp5;  // r = +5  -> slot ni+10
      // slot(ni, r) = ni + r + RAD = ni + j, j = 0..10
      float* col = colbase + ni * NB;   // &h[ni][lane]
#pragma unroll
      for (int j = 0; j < 11; ++j)
        atomicAdd(&col[j * NB], w[j]);  // ds_add_f32, imm offset j*256B
    }
  }
  __syncthreads();

  // Fold 64 columns -> 1 for the 64 real bins (slots RAD..RAD+63).
#pragma unroll
  for (int st = 32; st >= 1; st >>= 1) {
    for (int idx = tid; idx < NB * st; idx += 256) {
      int s = idx / st, c = idx % st;   // st is pow2 after unroll -> shifts
      h[s + RAD][c] += h[s + RAD][c + st];
    }
    __syncthreads();
  }
  if (tid < NB)
    part[((size_t)ct * SPLIT + seg) * NB + tid] = h[tid + RAD][0];
}

// Per-channel: sum segment partials, normalize, cumsum, sum |cdf diff|.
// 24 blocks x 64 threads; lane = bin. Writes chanloss[c].
__global__ __launch_bounds__(64) void chml_chan(const float* __restrict__ part,
                                                float* __restrict__ chanloss) {
  const int c    = blockIdx.x;
  const int lane = threadIdx.x;
  float vp = 0.0f, vt = 0.0f;
#pragma unroll
  for (int s = 0; s < SPLIT; ++s) {
    vp += part[((size_t)c * SPLIT + s) * NB + lane];
    vt += part[((size_t)(c + NCH) * SPLIT + s) * NB + lane];
  }
  // inclusive prefix scan across 64 lanes
#pragma unroll
  for (int off = 1; off < 64; off <<= 1) {
    float up = __shfl_up(vp, off, 64);
    float ut = __shfl_up(vt, off, 64);
    if (lane >= off) { vp += up; vt += ut; }
  }
  float totp = __shfl(vp, 63, 64);
  float tott = __shfl(vt, 63, 64);
  float l = fabsf(vp / (totp + 1e-7f) - vt / (tott + 1e-7f));
#pragma unroll
  for (int off = 32; off >= 1; off >>= 1) l += __shfl_xor(l, off, 64);
  if (lane == 0) chanloss[c] = l;
}

// Final: mean over 24*64 terms.
__global__ __launch_bounds__(64) void chml_final(const float* __restrict__ chanloss,
                                                 float* __restrict__ out) {
  const int lane = threadIdx.x;
  float l = (lane < NCH) ? chanloss[lane] : 0.0f;
#pragma unroll
  for (int off = 32; off >= 1; off >>= 1) l += __shfl_xor(l, off, 64);
  if (lane == 0) out[0] = l * (1.0f / (float)(NCH * NB));
}

extern "C" void kernel_launch(void* const* d_in, const int* in_sizes, int n_in,
                              void* d_out, int out_size, void* d_ws, size_t ws_size,
                              hipStream_t stream) {
  const float* pred = (const float*)d_in[0];
  const float* targ = (const float*)d_in[1];
  float* part     = (float*)d_ws;                       // 48*32*64 floats = 384 KB
  float* chanloss = part + (size_t)2 * NCH * SPLIT * NB; // +24 floats

  dim3 grid(SPLIT, 2 * NCH);
  chml_hist<<<grid, 256, 0, stream>>>(pred, targ, part);
  chml_chan<<<NCH, 64, 0, stream>>>(part, chanloss);
  chml_final<<<1, 64, 0, stream>>>(chanloss, (float*)d_out);
}

// Round 2
// 79.328 us; speedup vs baseline: 2.9714x; 2.9714x over previous
//
#include <hip/hip_runtime.h>

#define NB 64        // bins
#define HW 65536     // pixels per channel (256*256)
#define NCH 24       // B*C = 8*3
#define SPLIT 32     // segments per channel-image
#define RAD 5        // truncation radius: dropped mass < 1.5e-7 relative
#define ROWS 75      // padded per-thread row: 74 slots + 1 pad (stride 75 ≡ 11 mod 32)

// w_j(x) = exp(-2048*(x - j/63)^2) = exp(-K*(f-j)^2), f = 63x, K = 2048/3969.
// For j = ni + r (ni = round(f), d = f - ni):
//   w = exp(-K*(d-r)^2) = w0 * (e^{2Kd})^r * C_r,  w0 = e^{-K d^2}, C_r = e^{-K r^2}
// -> 3 transcendentals per pixel, 11 taps (|r| <= 5).
//
// Accumulation: per-THREAD private LDS ROW h[tid][75] (transposed vs r0):
//   - a pixel's 11 taps are CONTIGUOUS floats -> LLVM merges the b32 ops into
//     ds_read2_b32 / ds_write2_b32 -> ~12 DS ops/pixel instead of 22.
//   - no atomics (r1 showed ds atomics cost ~200 cyc each), no races: private row.
//   - RAW across a thread's consecutive pixels is safe: DS ops complete in
//     order per wave, and reads of pixel e+1 are issued after writes of e.
//   - row stride 75 floats (300 B) ≡ 11 mod 32 banks: lane->bank is a bijection
//     (odd multiplier) + random ni -> ~2 lanes/bank (free).
//   - tap reads are issued BEFORE the exp/weight ladder so the ~120-cyc LDS
//     latency is covered by ~74 cyc of independent VALU work.
__global__ __launch_bounds__(256) void chml_hist(const float* __restrict__ pred,
                                                 const float* __restrict__ targ,
                                                 float* __restrict__ part) {
  const int seg = blockIdx.x;   // 0..SPLIT-1
  const int ct  = blockIdx.y;   // 0..2*NCH-1
  const float* src = (ct < NCH) ? (pred + (size_t)ct * HW)
                                : (targ + (size_t)(ct - NCH) * HW);
  const int tid = threadIdx.x;

  __shared__ float h[256 * ROWS];   // 76.8 KB -> 2 blocks/CU
  {
    float4* hz = (float4*)h;
#pragma unroll 4
    for (int i = tid; i < 256 * ROWS / 4; i += 256)
      hz[i] = make_float4(0.f, 0.f, 0.f, 0.f);
  }
  __syncthreads();

  const float K  = 0.51599899f;      // 2048/3969
  const float C1 = 5.96905619e-01f;  // exp(-K*1)
  const float C2 = 1.26927917e-01f;  // exp(-K*4)
  const float C3 = 9.61165782e-03f;  // exp(-K*9)
  const float C4 = 2.59240329e-04f;  // exp(-K*16)
  const float C5 = 2.49029640e-06f;  // exp(-K*25)

  // segment = 2048 elems = 512 float4; 256 threads x 2, coalesced.
  // Both global loads issued up front (in flight during first pixels).
  const float4* s4 = (const float4*)(src + (size_t)seg * (HW / SPLIT));
  float4 P0 = s4[tid];
  float4 P1 = s4[256 + tid];
  float* const hrow = &h[tid * ROWS];

#pragma unroll
  for (int k = 0; k < 2; ++k) {
    float4 p = (k == 0) ? P0 : P1;
    float pe[4] = {p.x, p.y, p.z, p.w};
#pragma unroll
    for (int e = 0; e < 4; ++e) {
      float f = pe[e] * 63.0f;
      float n = rintf(f);
      float d = f - n;            // [-0.5, 0.5]
      int  ni = (int)n;           // 0..63
      float* tp = hrow + ni;      // taps at tp[0..10] (slots ni..ni+10)
      // ---- issue tap reads first (merged to ds_read2_b32 by the compiler)
      float t[11];
#pragma unroll
      for (int j = 0; j < 11; ++j) t[j] = tp[j];
      // ---- weight ladder overlaps the read latency
      float w0 = __expf(d * d * -K);
      float mp = __expf(d * (2.0f * K));   // e^{+2Kd}
      float mn = __expf(d * (-2.0f * K));  // e^{-2Kd}
      float mp2 = mp * mp, mp3 = mp2 * mp, mp4 = mp2 * mp2, mp5 = mp4 * mp;
      float mn2 = mn * mn, mn3 = mn2 * mn, mn4 = mn2 * mn2, mn5 = mn4 * mn;
      float A1 = w0 * C1, A2 = w0 * C2, A3 = w0 * C3, A4 = w0 * C4, A5 = w0 * C5;
      float w[11];
      w[0]  = A5 * mn5;  // r = -5
      w[1]  = A4 * mn4;
      w[2]  = A3 * mn3;
      w[3]  = A2 * mn2;
      w[4]  = A1 * mn;
      w[5]  = w0;        // r = 0
      w[6]  = A1 * mp;
      w[7]  = A2 * mp2;
      w[8]  = A3 * mp3;
      w[9]  = A4 * mp4;
      w[10] = A5 * mp5;  // r = +5
      // ---- RMW writeback (merged to ds_write2_b32)
#pragma unroll
      for (int j = 0; j < 11; ++j) tp[j] = t[j] + w[j];
    }
  }
  __syncthreads();

  // Fold 256 rows -> 64 bins. Thread tid sums bin (tid&63) over rows
  // [ (tid>>6)*64 .. +63 ]; then 4 partials per bin combined via LDS.
  {
    const int b = tid & 63, c = tid >> 6;
    const float* colp = &h[(c * 64) * ROWS + b + RAD];
    float acc = 0.f;
#pragma unroll 16
    for (int r = 0; r < 64; ++r) acc += colp[r * ROWS];
    __syncthreads();
    h[tid] = acc;                 // partial (c, b)
    __syncthreads();
    if (tid < NB) {
      float v = h[tid] + h[64 + tid] + h[128 + tid] + h[192 + tid];
      part[((size_t)ct * SPLIT + seg) * NB + tid] = v;
    }
  }
}

// Per-channel: sum segment partials, normalize, cumsum, sum |cdf diff|.
// 24 blocks x 64 threads; lane = bin. Writes chanloss[c].
__global__ __launch_bounds__(64) void chml_chan(const float* __restrict__ part,
                                                float* __restrict__ chanloss) {
  const int c    = blockIdx.x;
  const int lane = threadIdx.x;
  float vp = 0.0f, vt = 0.0f;
#pragma unroll
  for (int s = 0; s < SPLIT; ++s) {
    vp += part[((size_t)c * SPLIT + s) * NB + lane];
    vt += part[((size_t)(c + NCH) * SPLIT + s) * NB + lane];
  }
  // inclusive prefix scan across 64 lanes
#pragma unroll
  for (int off = 1; off < 64; off <<= 1) {
    float up = __shfl_up(vp, off, 64);
    float ut = __shfl_up(vt, off, 64);
    if (lane >= off) { vp += up; vt += ut; }
  }
  float totp = __shfl(vp, 63, 64);
  float tott = __shfl(vt, 63, 64);
  float l = fabsf(vp / (totp + 1e-7f) - vt / (tott + 1e-7f));
#pragma unroll
  for (int off = 32; off >= 1; off >>= 1) l += __shfl_xor(l, off, 64);
  if (lane == 0) chanloss[c] = l;
}

// Final: mean over 24*64 terms.
__global__ __launch_bounds__(64) void chml_final(const float* __restrict__ chanloss,
                                                 float* __restrict__ out) {
  const int lane = threadIdx.x;
  float l = (lane < NCH) ? chanloss[lane] : 0.0f;
#pragma unroll
  for (int off = 32; off >= 1; off >>= 1) l += __shfl_xor(l, off, 64);
  if (lane == 0) out[0] = l * (1.0f / (float)(NCH * NB));
}

extern "C" void kernel_launch(void* const* d_in, const int* in_sizes, int n_in,
                              void* d_out, int out_size, void* d_ws, size_t ws_size,
                              hipStream_t stream) {
  const float* pred = (const float*)d_in[0];
  const float* targ = (const float*)d_in[1];
  float* part     = (float*)d_ws;                       // 48*32*64 floats = 384 KB
  float* chanloss = part + (size_t)2 * NCH * SPLIT * NB; // +24 floats

  dim3 grid(SPLIT, 2 * NCH);
  chml_hist<<<grid, 256, 0, stream>>>(pred, targ, part);
  chml_chan<<<NCH, 64, 0, stream>>>(part, chanloss);
  chml_final<<<1, 64, 0, stream>>>(chanloss, (float*)d_out);
}